// Round 3
// baseline (558.905 us; speedup 1.0000x reference)
//
#include <hip/hip_runtime.h>
#include <math.h>

#define N_SAMPLES 65536
#define N_FRAMES  128
#define NUM_COEFF 6
#define NSEG      126        // N_FRAMES - 2
#define VEC_SIZE  808
#define ZCLAMP    (VEC_SIZE - 7)   // 801

// ---- workspace layout (byte offsets) ----
#define WS_X     0           // float x[65536]
#define WS_VALS  262144      // float vals8[65536][8]; slot 7 = pre-biased ring idx
#define WS_BMIN  2359296     // int Bg[257]: per-block z-min (block 256 = INT_MAX)

// ---------------------------------------------------------------------------
// K1: fused front-end. Blocks 0..255: spline -> vals8 (+ per-block z-min).
// Block 256: exc first-order IIR via affine scan.
// ---------------------------------------------------------------------------
__global__ __launch_bounds__(256) void k_front(
    const float* __restrict__ delay_len,
    const float* __restrict__ raw_gain,
    const float* __restrict__ raw_coeff,
    const float* __restrict__ exc,
    const float* __restrict__ burst,
    float* __restrict__ ws)
{
    float* xarr  = ws + WS_X / 4;
    float* vals8 = ws + WS_VALS / 4;
    int* Bg = (int*)((char*)ws + WS_BMIN);
    const int tid = threadIdx.x;
    const int b = blockIdx.x;

    if (b == 256) {
        // ---- exc IIR: x[t] = burst[t] - a[t]*x[t-1], affine scan ----
        __shared__ float sm[256], sc[256];
        const int base = tid * 256;
        float m = 1.f, c = 0.f;
        for (int i = 0; i < 256; ++i) {
            const float a = exc[base + i];
            const float x = burst[base + i];
            m = -a * m;
            c = x - a * c;
        }
        sm[tid] = m; sc[tid] = c;
        __syncthreads();
        for (int off = 1; off < 256; off <<= 1) {
            const float cm = sm[tid], cc = sc[tid];
            float pm = 1.f, pc = 0.f;
            if (tid >= off) { pm = sm[tid - off]; pc = sc[tid - off]; }
            __syncthreads();
            if (tid >= off) { sm[tid] = cm * pm; sc[tid] = cm * pc + cc; }
            __syncthreads();
        }
        float y = (tid == 0) ? 0.f : sc[tid - 1];
        for (int i = 0; i < 256; ++i) {
            const float a = exc[base + i];
            y = burst[base + i] - a * y;
            xarr[base + i] = y;
        }
        if (tid == 0) Bg[256] = 0x7fffffff;
        return;
    }

    // ---- spline path ----
    __shared__ float Y[7][N_FRAMES];
    __shared__ float M[7][N_FRAMES];
    __shared__ double cp[NSEG];
    __shared__ double dp[7][NSEG];
    __shared__ int bmin;

    if (tid < N_FRAMES) {
        float s[NUM_COEFF];
        float sum = 0.f;
        for (int j = 0; j < NUM_COEFF; ++j) {
            s[j] = 1.f / (1.f + expf(-raw_coeff[tid * NUM_COEFF + j]));
            sum += s[j];
        }
        const float gain = 1.f / (1.f + expf(-raw_gain[0]));
        for (int j = 0; j < NUM_COEFF; ++j)
            Y[1 + j][tid] = s[j] / sum * gain;
        Y[0][tid] = delay_len[tid];
    }
    if (tid == 0) bmin = 0x7fffffff;
    __syncthreads();

    if (tid == 0) {
        cp[0] = 0.25;
        for (int i = 1; i < NSEG; ++i) cp[i] = 1.0 / (4.0 - cp[i - 1]);
    }
    __syncthreads();

    if (tid < 7) {
        const float* y = Y[tid];
        const double inv_h2 = 127.0 * 127.0;
        double prev = 6.0 * ((double)y[2] - 2.0 * (double)y[1] + (double)y[0]) * inv_h2 * 0.25;
        dp[tid][0] = prev;
        for (int i = 1; i < NSEG; ++i) {
            double ri = 6.0 * ((double)y[i + 2] - 2.0 * (double)y[i + 1] + (double)y[i]) * inv_h2;
            prev = (ri - prev) * cp[i];   // cp[i] == 1/(4 - cp[i-1])
            dp[tid][i] = prev;
        }
        float* Mc = M[tid];
        Mc[0] = 0.f; Mc[N_FRAMES - 1] = 0.f;
        double mi = dp[tid][NSEG - 1];
        Mc[NSEG] = (float)mi;
        for (int i = NSEG - 2; i >= 0; --i) {
            mi = dp[tid][i] - cp[i] * mi;
            Mc[i + 1] = (float)mi;
        }
    }
    __syncthreads();

    const int t = b * 256 + tid;
    const float h = 1.0f / 127.0f;
    const float tf = (float)t * (1.0f / 65535.0f);
    int idx = (int)floorf(tf * 127.0f);
    idx = min(max(idx, 0), 126);
    const float s = tf - (float)idx * h;
    const float s2 = s * s;
    const float s3 = s2 * s;

    float o[7];
#pragma unroll
    for (int c = 0; c < 7; ++c) {
        const float yi  = Y[c][idx];
        const float yi1 = Y[c][idx + 1];
        const float Mi  = M[c][idx];
        const float Mi1 = M[c][idx + 1];
        const float bb = (yi1 - yi) / h - h * (2.f * Mi + Mi1) / 6.f;
        o[c] = yi + bb * s + 0.5f * Mi * s2 + (Mi1 - Mi) * s3 / (6.f * h);
    }
    const float delay = o[0];
    int z = (int)floorf(delay);
    const float alfa = delay - (float)z;
    z = min(max(z, 0), ZCLAMP);

    float v[8];
    v[0] = -((1.f - alfa) * o[1]);
#pragma unroll
    for (int j = 1; j <= 5; ++j)
        v[j] = -(alfa * o[j] + (1.f - alfa) * o[j + 1]);
    v[6] = -(alfa * o[6]);
    // pre-biased ring index for k_ks: ((t-1-z) mod 1024) + 1018, exact in f32
    v[7] = (float)(((t - 1 - z) & 1023) + 1018);

    float4* vp = (float4*)(vals8 + (size_t)t * 8);
    vp[0] = make_float4(v[0], v[1], v[2], v[3]);
    vp[1] = make_float4(v[4], v[5], v[6], v[7]);

    atomicMin(&bmin, z);
    __syncthreads();
    if (tid == 0) Bg[b] = bmin;
}

// ---------------------------------------------------------------------------
// K2: chunked KS recurrence — SINGLE WAVE, no barriers.
// C = min(zmin+1, 128). Each lane computes samples S+lane and S+64+lane
// (the latter only when C > 64): all taps have lag >= z+1 >= C, so every
// sample in a chunk depends only on earlier chunks. LDS ops from one wave
// execute in order -> write(chunk c) / read(chunk c+1) needs no sync.
// Depth-4 register prefetch of (vals, x) hides global-load latency.
// Doubled 2048-entry ring makes the 7 taps contiguous dwords.
// ---------------------------------------------------------------------------
__global__ __launch_bounds__(64) void k_ks(
    const float* __restrict__ ws_c,
    float* __restrict__ out)
{
    __shared__ float ring2[2048];
    const int lane = threadIdx.x;
    const float* xarr  = ws_c + WS_X / 4;
    const float* vals8 = ws_c + WS_VALS / 4;
    const int* Bg = (const int*)((const char*)ws_c + WS_BMIN);

    for (int i = lane; i < 2048; i += 64) ring2[i] = 0.f;

    // global z-min over 257 per-block mins, wave butterfly
    int m = 0x7fffffff;
    for (int i = lane; i < 257; i += 64) m = min(m, Bg[i]);
#pragma unroll
    for (int off = 32; off; off >>= 1) m = min(m, __shfl_xor(m, off));
    int C = m + 1;
    if (C > 128) C = 128;
    if (C < 1) C = 1;
    const int C4 = 4 * C;
    const bool hi_on = (C > 64);

    // 4 prefetch stages x 2 samples x (float4 a, float4 b, float x)
    float4 zf4 = {0.f, 0.f, 0.f, 0.f};
    float4 A0L = zf4, B0L = zf4, A0H = zf4, B0H = zf4;
    float4 A1L = zf4, B1L = zf4, A1H = zf4, B1H = zf4;
    float4 A2L = zf4, B2L = zf4, A2H = zf4, B2H = zf4;
    float4 A3L = zf4, B3L = zf4, A3H = zf4, B3H = zf4;
    float X0L = 0.f, X0H = 0.f, X1L = 0.f, X1H = 0.f;
    float X2L = 0.f, X2H = 0.f, X3L = 0.f, X3H = 0.f;

#define LOADS(AL, BL, XL, AH, BH, XH, SS)                                      \
    do {                                                                       \
        const int tp = (SS) + lane;                                            \
        if (tp < N_SAMPLES) {                                                  \
            const float4* vp = (const float4*)(vals8 + (size_t)tp * 8);        \
            (AL) = vp[0]; (BL) = vp[1]; (XL) = xarr[tp];                       \
        }                                                                      \
        const int tq = (SS) + 64 + lane;                                       \
        if (hi_on && tq < N_SAMPLES) {                                         \
            const float4* vq = (const float4*)(vals8 + (size_t)tq * 8);        \
            (AH) = vq[0]; (BH) = vq[1]; (XH) = xarr[tq];                       \
        }                                                                      \
    } while (0)

#define BODY(AL, BL, XL, AH, BH, XH, SS)                                       \
    do {                                                                       \
        const int t0 = (SS) + lane;                                            \
        const int i0 = (int)(BL).w;  /* pre-biased ring index */               \
        const float d0 = (AL).x * ring2[i0 + 6] + (AL).y * ring2[i0 + 5]       \
                       + (AL).z * ring2[i0 + 4] + (AL).w * ring2[i0 + 3]       \
                       + (BL).x * ring2[i0 + 2] + (BL).y * ring2[i0 + 1]       \
                       + (BL).z * ring2[i0];                                   \
        const float y0 = (XL) - d0;                                           \
        const int t1 = t0 + 64;                                                \
        const int i1 = (int)(BH).w;                                            \
        const float d1 = (AH).x * ring2[i1 + 6] + (AH).y * ring2[i1 + 5]       \
                       + (AH).z * ring2[i1 + 4] + (AH).w * ring2[i1 + 3]       \
                       + (BH).x * ring2[i1 + 2] + (BH).y * ring2[i1 + 1]       \
                       + (BH).z * ring2[i1];                                   \
        const float y1 = (XH) - d1;                                           \
        if ((lane < C) && (t0 < N_SAMPLES)) {                                  \
            const int w = t0 & 1023;                                           \
            ring2[w] = y0; ring2[w + 1024] = y0; out[t0] = y0;                 \
        }                                                                      \
        if ((lane + 64 < C) && (t1 < N_SAMPLES)) {                             \
            const int w = t1 & 1023;                                           \
            ring2[w] = y1; ring2[w + 1024] = y1; out[t1] = y1;                 \
        }                                                                      \
        LOADS(AL, BL, XL, AH, BH, XH, (SS) + C4);                              \
    } while (0)

    // prologue: prefetch chunks 0..3
    LOADS(A0L, B0L, X0L, A0H, B0H, X0H, 0);
    LOADS(A1L, B1L, X1L, A1H, B1H, X1H, C);
    LOADS(A2L, B2L, X2L, A2H, B2H, X2H, 2 * C);
    LOADS(A3L, B3L, X3L, A3H, B3H, X3H, 3 * C);

    for (int S = 0; S < N_SAMPLES; S += C4) {
        BODY(A0L, B0L, X0L, A0H, B0H, X0H, S);
        BODY(A1L, B1L, X1L, A1H, B1H, X1H, S + C);
        BODY(A2L, B2L, X2L, A2H, B2H, X2H, S + 2 * C);
        BODY(A3L, B3L, X3L, A3H, B3H, X3H, S + 3 * C);
    }
#undef BODY
#undef LOADS
}

// ---------------------------------------------------------------------------
extern "C" void kernel_launch(void* const* d_in, const int* in_sizes, int n_in,
                              void* d_out, int out_size, void* d_ws, size_t ws_size,
                              hipStream_t stream)
{
    const float* delay_len = (const float*)d_in[0];
    const float* raw_gain  = (const float*)d_in[1];
    const float* raw_coeff = (const float*)d_in[2];
    const float* exc       = (const float*)d_in[3];
    const float* burst     = (const float*)d_in[4];
    float* ws  = (float*)d_ws;
    float* out = (float*)d_out;

    hipLaunchKernelGGL(k_front, dim3(257), dim3(256), 0, stream,
                       delay_len, raw_gain, raw_coeff, exc, burst, ws);
    hipLaunchKernelGGL(k_ks, dim3(1), dim3(64), 0, stream, ws, out);
}

// Round 4
// 444.978 us; speedup vs baseline: 1.2560x; 1.2560x over previous
//
#include <hip/hip_runtime.h>
#include <math.h>

#define N_SAMPLES 65536
#define N_FRAMES  128
#define NUM_COEFF 6
#define NSEG      126        // N_FRAMES - 2
#define VEC_SIZE  808
#define ZCLAMP    (VEC_SIZE - 7)   // 801

// ---- workspace layout (byte offsets) ----
#define WS_X     0           // float x[65536]
#define WS_VALS  262144      // float vals8[65536][8]; slot 7 = pre-biased ring idx
#define WS_BMIN  2359296     // int Bg[257]: per-block z-min (block 256 = INT_MAX)

// ---------------------------------------------------------------------------
// K1: fused front-end (unchanged from round 3 — verified correct).
// Blocks 0..255: spline -> vals8 (+ per-block z-min). Block 256: exc IIR scan.
// ---------------------------------------------------------------------------
__global__ __launch_bounds__(256) void k_front(
    const float* __restrict__ delay_len,
    const float* __restrict__ raw_gain,
    const float* __restrict__ raw_coeff,
    const float* __restrict__ exc,
    const float* __restrict__ burst,
    float* __restrict__ ws)
{
    float* xarr  = ws + WS_X / 4;
    float* vals8 = ws + WS_VALS / 4;
    int* Bg = (int*)((char*)ws + WS_BMIN);
    const int tid = threadIdx.x;
    const int b = blockIdx.x;

    if (b == 256) {
        __shared__ float sm[256], sc[256];
        const int base = tid * 256;
        float m = 1.f, c = 0.f;
        for (int i = 0; i < 256; ++i) {
            const float a = exc[base + i];
            const float x = burst[base + i];
            m = -a * m;
            c = x - a * c;
        }
        sm[tid] = m; sc[tid] = c;
        __syncthreads();
        for (int off = 1; off < 256; off <<= 1) {
            const float cm = sm[tid], cc = sc[tid];
            float pm = 1.f, pc = 0.f;
            if (tid >= off) { pm = sm[tid - off]; pc = sc[tid - off]; }
            __syncthreads();
            if (tid >= off) { sm[tid] = cm * pm; sc[tid] = cm * pc + cc; }
            __syncthreads();
        }
        float y = (tid == 0) ? 0.f : sc[tid - 1];
        for (int i = 0; i < 256; ++i) {
            const float a = exc[base + i];
            y = burst[base + i] - a * y;
            xarr[base + i] = y;
        }
        if (tid == 0) Bg[256] = 0x7fffffff;
        return;
    }

    __shared__ float Y[7][N_FRAMES];
    __shared__ float M[7][N_FRAMES];
    __shared__ double cp[NSEG];
    __shared__ double dp[7][NSEG];
    __shared__ int bmin;

    if (tid < N_FRAMES) {
        float s[NUM_COEFF];
        float sum = 0.f;
        for (int j = 0; j < NUM_COEFF; ++j) {
            s[j] = 1.f / (1.f + expf(-raw_coeff[tid * NUM_COEFF + j]));
            sum += s[j];
        }
        const float gain = 1.f / (1.f + expf(-raw_gain[0]));
        for (int j = 0; j < NUM_COEFF; ++j)
            Y[1 + j][tid] = s[j] / sum * gain;
        Y[0][tid] = delay_len[tid];
    }
    if (tid == 0) bmin = 0x7fffffff;
    __syncthreads();

    if (tid == 0) {
        cp[0] = 0.25;
        for (int i = 1; i < NSEG; ++i) cp[i] = 1.0 / (4.0 - cp[i - 1]);
    }
    __syncthreads();

    if (tid < 7) {
        const float* y = Y[tid];
        const double inv_h2 = 127.0 * 127.0;
        double prev = 6.0 * ((double)y[2] - 2.0 * (double)y[1] + (double)y[0]) * inv_h2 * 0.25;
        dp[tid][0] = prev;
        for (int i = 1; i < NSEG; ++i) {
            double ri = 6.0 * ((double)y[i + 2] - 2.0 * (double)y[i + 1] + (double)y[i]) * inv_h2;
            prev = (ri - prev) * cp[i];
            dp[tid][i] = prev;
        }
        float* Mc = M[tid];
        Mc[0] = 0.f; Mc[N_FRAMES - 1] = 0.f;
        double mi = dp[tid][NSEG - 1];
        Mc[NSEG] = (float)mi;
        for (int i = NSEG - 2; i >= 0; --i) {
            mi = dp[tid][i] - cp[i] * mi;
            Mc[i + 1] = (float)mi;
        }
    }
    __syncthreads();

    const int t = b * 256 + tid;
    const float h = 1.0f / 127.0f;
    const float tf = (float)t * (1.0f / 65535.0f);
    int idx = (int)floorf(tf * 127.0f);
    idx = min(max(idx, 0), 126);
    const float s = tf - (float)idx * h;
    const float s2 = s * s;
    const float s3 = s2 * s;

    float o[7];
#pragma unroll
    for (int c = 0; c < 7; ++c) {
        const float yi  = Y[c][idx];
        const float yi1 = Y[c][idx + 1];
        const float Mi  = M[c][idx];
        const float Mi1 = M[c][idx + 1];
        const float bb = (yi1 - yi) / h - h * (2.f * Mi + Mi1) / 6.f;
        o[c] = yi + bb * s + 0.5f * Mi * s2 + (Mi1 - Mi) * s3 / (6.f * h);
    }
    const float delay = o[0];
    int z = (int)floorf(delay);
    const float alfa = delay - (float)z;
    z = min(max(z, 0), ZCLAMP);

    float v[8];
    v[0] = -((1.f - alfa) * o[1]);
#pragma unroll
    for (int j = 1; j <= 5; ++j)
        v[j] = -(alfa * o[j] + (1.f - alfa) * o[j + 1]);
    v[6] = -(alfa * o[6]);
    v[7] = (float)(((t - 1 - z) & 1023) + 1018);   // pre-biased ring idx

    float4* vp = (float4*)(vals8 + (size_t)t * 8);
    vp[0] = make_float4(v[0], v[1], v[2], v[3]);
    vp[1] = make_float4(v[4], v[5], v[6], v[7]);

    atomicMin(&bmin, z);
    __syncthreads();
    if (tid == 0) Bg[b] = bmin;
}

// ---------------------------------------------------------------------------
// K2: producer/consumer KS recurrence. 128 threads = 2 waves, NO barriers
// after init. Wave 0 = consumer (sole owner of the LDS ring -> tap RAW is
// same-wave in-order, zero sync). Wave 1 = producer (global -> LDS staging,
// depth-3 register rotation; per-slot monotone chunk-ID flags; backpressure
// via consumer progress word).
// ---------------------------------------------------------------------------

// XOR swizzle at float4 granularity: conflict-free b128 for both the
// producer's 4-consecutive-f4 writes and the consumer's stride-2-f4 reads.
#define SWZ(f) ((f) ^ (((f) >> 3) & 7))

__global__ __launch_bounds__(128) void k_ks(
    const float* __restrict__ ws_c,
    float* __restrict__ out)
{
    __shared__ float  ring2[2048];
    __shared__ float4 stg[8][256];     // 8 slots x 128 samples x 32B
    __shared__ float  xstg[8][128];
    __shared__ int    flags[8];
    __shared__ int    ctl[2];          // [0] = consumer progress (chunk id)
    __shared__ int    meta[2];

    const int tid = threadIdx.x;
    const float* xarr  = ws_c + WS_X / 4;
    const float* vals8 = ws_c + WS_VALS / 4;
    const int* Bg = (const int*)((const char*)ws_c + WS_BMIN);

    for (int i = tid; i < 2048; i += 128) ring2[i] = 0.f;
    if (tid < 8) flags[tid] = -1;
    if (tid < 2) ctl[tid] = -1;

    // global z-min over 257 per-block mins
    int m = 0x7fffffff;
    for (int i = tid; i < 257; i += 128) m = min(m, Bg[i]);
#pragma unroll
    for (int off = 32; off; off >>= 1) m = min(m, __shfl_xor(m, off));
    if ((tid & 63) == 0) meta[tid >> 6] = m;
    __syncthreads();                    // the ONLY barrier

    int C = min(meta[0], meta[1]) + 1;
    if (C > 128) C = 128;
    if (C < 1) C = 1;
    const int nch = (N_SAMPLES + C - 1) / C;
    const int lane = tid & 63;

    if (tid >= 64) {
        // ================= PRODUCER (wave 1) =================
        float4 Ar0, Ar1, Ar2, Ar3; float Ax0, Ax1;
        float4 Br0, Br1, Br2, Br3; float Bx0, Bx1;
        float4 Cr0, Cr1, Cr2, Cr3; float Cx0, Cx1;
        volatile int* vcp = ctl;
        volatile int* vfl = flags;

#define PLOAD(R0, R1, R2, R3, X0, X1, JJ)                                      \
    do {                                                                       \
        const long s = (long)(JJ) * C;                                         \
        long si = s + 2 * (long)lane;                                          \
        if (si > N_SAMPLES - 2) si = N_SAMPLES - 2;                            \
        const float4* gv = (const float4*)(vals8 + si * 8);                    \
        R0 = gv[0]; R1 = gv[1]; R2 = gv[2]; R3 = gv[3];                        \
        long xi0 = s + lane;        if (xi0 > N_SAMPLES - 1) xi0 = N_SAMPLES - 1; \
        long xi1 = s + 64 + lane;   if (xi1 > N_SAMPLES - 1) xi1 = N_SAMPLES - 1; \
        X0 = xarr[xi0]; X1 = xarr[xi1];                                        \
    } while (0)

#define PSTEP(R0, R1, R2, R3, X0, X1, Z0, Z1, Z2, Z3, ZX0, ZX1, JJ)            \
    do {                                                                       \
        const int j_ = (JJ);                                                   \
        while (vcp[0] < j_ - 7) { __builtin_amdgcn_s_sleep(1); }               \
        if (j_ + 2 < nch) PLOAD(Z0, Z1, Z2, Z3, ZX0, ZX1, j_ + 2);             \
        const int sl_ = j_ & 7;                                                \
        /* lane covers samples 2*lane, 2*lane+1 of the chunk */                \
        { const int s0 = 2 * lane;  /* sample index base */                    \
          long sg = (long)j_ * C + s0;                                         \
          /* write only real samples; clamp duplicates land harmlessly */      \
          (void)sg;                                                            \
          const int fb = 4 * lane;                                             \
          stg[sl_][SWZ(fb)]     = R0;                                          \
          stg[sl_][SWZ(fb + 1)] = R1;                                          \
          stg[sl_][SWZ(fb + 2)] = R2;                                          \
          stg[sl_][SWZ(fb + 3)] = R3;                                          \
          xstg[sl_][lane]      = X0;                                           \
          xstg[sl_][lane + 64] = X1; }                                         \
        asm volatile("" ::: "memory");                                         \
        vfl[sl_] = j_;                                                         \
    } while (0)

        PLOAD(Ar0, Ar1, Ar2, Ar3, Ax0, Ax1, 0);
        if (nch > 1) PLOAD(Br0, Br1, Br2, Br3, Bx0, Bx1, 1);
        for (int j = 0; j < nch; j += 3) {
            PSTEP(Ar0, Ar1, Ar2, Ar3, Ax0, Ax1, Cr0, Cr1, Cr2, Cr3, Cx0, Cx1, j);
            if (j + 1 < nch)
                PSTEP(Br0, Br1, Br2, Br3, Bx0, Bx1, Ar0, Ar1, Ar2, Ar3, Ax0, Ax1, j + 1);
            if (j + 2 < nch)
                PSTEP(Cr0, Cr1, Cr2, Cr3, Cx0, Cx1, Br0, Br1, Br2, Br3, Bx0, Bx1, j + 2);
        }
#undef PSTEP
#undef PLOAD
        return;
    }

    // ================= CONSUMER (wave 0) =================
    float4 Xal, Xbl, Xah, Xbh; float Xxl, Xxh;
    float4 Yal, Ybl, Yah, Ybh; float Yxl, Yxh;
    volatile int* vfl = flags;
    volatile int* vcp = ctl;
    int fv;

#define LOADSTG(AL, BL, AH, BH, XL, XH, CC)                                    \
    do {                                                                       \
        const int sl_ = (CC) & 7;                                              \
        const int f0 = 2 * lane;                                               \
        const int f1 = 2 * (lane + 64);                                        \
        AL = stg[sl_][SWZ(f0)];                                                \
        BL = stg[sl_][SWZ(f0 + 1)];                                            \
        AH = stg[sl_][SWZ(f1)];                                                \
        BH = stg[sl_][SWZ(f1 + 1)];                                            \
        XL = xstg[sl_][lane];                                                  \
        XH = xstg[sl_][lane + 64];                                             \
    } while (0)

#define CSTEP(AL, BL, AH, BH, XL, XH, NAL, NBL, NAH, NBH, NXL, NXH, CC)        \
    do {                                                                       \
        const int c_ = (CC);                                                   \
        const int S_ = c_ * C;                                                 \
        const int t0 = S_ + lane;                                              \
        int i0 = (int)(BL).w; i0 = min(max(i0, 0), 2041);                      \
        int i1 = (int)(BH).w; i1 = min(max(i1, 0), 2041);                      \
        const float d0 = (AL).x * ring2[i0 + 6] + (AL).y * ring2[i0 + 5]       \
                       + (AL).z * ring2[i0 + 4] + (AL).w * ring2[i0 + 3]       \
                       + (BL).x * ring2[i0 + 2] + (BL).y * ring2[i0 + 1]       \
                       + (BL).z * ring2[i0];                                   \
        const float y0 = (XL) - d0;                                            \
        const float d1 = (AH).x * ring2[i1 + 6] + (AH).y * ring2[i1 + 5]       \
                       + (AH).z * ring2[i1 + 4] + (AH).w * ring2[i1 + 3]       \
                       + (BH).x * ring2[i1 + 2] + (BH).y * ring2[i1 + 1]       \
                       + (BH).z * ring2[i1];                                   \
        const float y1 = (XH) - d1;                                            \
        if ((lane < C) && (t0 < N_SAMPLES)) {                                  \
            const int w = t0 & 1023;                                           \
            ring2[w] = y0; ring2[w + 1024] = y0; out[t0] = y0;                 \
        }                                                                      \
        const int t1 = t0 + 64;                                                \
        if ((lane + 64 < C) && (t1 < N_SAMPLES)) {                             \
            const int w = t1 & 1023;                                           \
            ring2[w] = y1; ring2[w + 1024] = y1; out[t1] = y1;                 \
        }                                                                      \
        if (c_ + 1 < nch) {                                                    \
            if (fv < c_ + 1) {                                                 \
                do { fv = vfl[(c_ + 1) & 7]; } while (fv < c_ + 1);            \
            }                                                                  \
            asm volatile("" ::: "memory");                                     \
            LOADSTG(NAL, NBL, NAH, NBH, NXL, NXH, c_ + 1);                     \
        }                                                                      \
        vcp[0] = c_;                                                           \
        fv = (c_ + 2 < nch) ? vfl[(c_ + 2) & 7] : 0x7fffffff;                  \
    } while (0)

    // prologue: wait for chunk 0
    while (vfl[0] < 0) {}
    asm volatile("" ::: "memory");
    LOADSTG(Xal, Xbl, Xah, Xbh, Xxl, Xxh, 0);
    fv = vfl[1 & 7];

    for (int c = 0; c < nch; c += 2) {
        CSTEP(Xal, Xbl, Xah, Xbh, Xxl, Xxh,
              Yal, Ybl, Yah, Ybh, Yxl, Yxh, c);
        if (c + 1 < nch)
            CSTEP(Yal, Ybl, Yah, Ybh, Yxl, Yxh,
                  Xal, Xbl, Xah, Xbh, Xxl, Xxh, c + 1);
    }
#undef CSTEP
#undef LOADSTG
}

// ---------------------------------------------------------------------------
extern "C" void kernel_launch(void* const* d_in, const int* in_sizes, int n_in,
                              void* d_out, int out_size, void* d_ws, size_t ws_size,
                              hipStream_t stream)
{
    const float* delay_len = (const float*)d_in[0];
    const float* raw_gain  = (const float*)d_in[1];
    const float* raw_coeff = (const float*)d_in[2];
    const float* exc       = (const float*)d_in[3];
    const float* burst     = (const float*)d_in[4];
    float* ws  = (float*)d_ws;
    float* out = (float*)d_out;

    hipLaunchKernelGGL(k_front, dim3(257), dim3(256), 0, stream,
                       delay_len, raw_gain, raw_coeff, exc, burst, ws);
    hipLaunchKernelGGL(k_ks, dim3(1), dim3(128), 0, stream, ws, out);
}